// Round 11
// baseline (179.170 us; speedup 1.0000x reference)
//
#include <hip/hip_runtime.h>
#include <math.h>

#define F_IN 128
#define NHD 8
#define FEAT 128   // NHD*FO
#define NEG_SLOPE 0.2f
#define LN_EPS 1e-5f
#define NPQ 16     // nodes per k_ba block
#define CAP 48     // per-node slot capacity; deg>CAP -> fallback
#define EPB 4096   // edges scattered per phase-A block (512 thr x 8)
#define WCOLS 144  // 128 xp cols + 8 a_src cols + 8 a_dst cols

typedef __bf16 v8bf __attribute__((ext_vector_type(8)));
typedef __bf16 v4bf __attribute__((ext_vector_type(4)));
typedef __bf16 v2bf __attribute__((ext_vector_type(2)));
typedef float f32x4 __attribute__((ext_vector_type(4)));

// Build WT_ext[144][128]: cols 0..127 = W^T (bf16); cols 128..135 = W @ att_src
// folded per head; cols 136..143 = W @ att_dst. Also zeroes the per-node
// scatter counters (stream-ordered before k_fused).
__global__ __launch_bounds__(256) void k_wt(const float* __restrict__ W,
                                            const float* __restrict__ att_src,
                                            const float* __restrict__ att_dst,
                                            __bf16* __restrict__ WT,
                                            int* __restrict__ nodecnt, int n) {
    int idx = blockIdx.x * 256 + threadIdx.x;
    if (idx < n) nodecnt[idx] = 0;
    if (idx < WCOLS * 128) {
        int c = idx >> 7, k = idx & 127;
        float v;
        if (c < 128) {
            v = W[k * 128 + c];
        } else if (c < 136) {
            int h = c - 128;
            float s = 0.f;
#pragma unroll
            for (int f = 0; f < 16; ++f) s += W[k * 128 + h * 16 + f] * att_src[h * 16 + f];
            v = s;
        } else {
            int h = c - 136;
            float s = 0.f;
#pragma unroll
            for (int f = 0; f < 16; ++f) s += W[k * 128 + h * 16 + f] * att_dst[h * 16 + f];
            v = s;
        }
        WT[c * 128 + k] = (__bf16)v;
    }
}

// Fused: blocks [0,Ga) = DIRECT per-node scatter (no counting sort): each
// edge does one global atomicAdd on its dst's counter and writes src into
// that node's slot list. Blocks [Ga,..) = MFMA GEMM, 64 rows/block.
__global__ __launch_bounds__(512) void k_fused(const float* __restrict__ x,
                                               const __bf16* __restrict__ WT,
                                               __bf16* __restrict__ xp16,
                                               float* __restrict__ a_src,
                                               float* __restrict__ a_dst,
                                               const int* __restrict__ src,
                                               const int* __restrict__ dst,
                                               int* __restrict__ nodelist,
                                               int* __restrict__ nodecnt,
                                               int n, int E, int Ga) {
    if ((int)blockIdx.x < Ga) {
        // ---- phase A: direct scatter ----
        int tid = threadIdx.x;
        long base0 = (long)blockIdx.x * EPB;
        long total = (long)E + n;
        int s0[8], d0[8];
        bool val[8];
        long e0 = base0 + (long)tid * 8;
        if (e0 + 7 < E) {
            int4 sa = *(const int4*)(src + e0);
            int4 sb = *(const int4*)(src + e0 + 4);
            int4 da = *(const int4*)(dst + e0);
            int4 db = *(const int4*)(dst + e0 + 4);
            s0[0] = sa.x; s0[1] = sa.y; s0[2] = sa.z; s0[3] = sa.w;
            s0[4] = sb.x; s0[5] = sb.y; s0[6] = sb.z; s0[7] = sb.w;
            d0[0] = da.x; d0[1] = da.y; d0[2] = da.z; d0[3] = da.w;
            d0[4] = db.x; d0[5] = db.y; d0[6] = db.z; d0[7] = db.w;
#pragma unroll
            for (int j = 0; j < 8; ++j) val[j] = true;
        } else {
#pragma unroll
            for (int j = 0; j < 8; ++j) {
                long e = e0 + j;
                val[j] = (e < total);
                s0[j] = d0[j] = 0;
                if (val[j]) {
                    if (e < E) { s0[j] = src[e]; d0[j] = dst[e]; }
                    else { s0[j] = d0[j] = (int)(e - E); }
                }
            }
        }
#pragma unroll
        for (int j = 0; j < 8; ++j) {
            if (val[j]) {
                int pos = atomicAdd(&nodecnt[d0[j]], 1);
                if (pos < CAP)
                    nodelist[(long)d0[j] * CAP + pos] = s0[j];
            }
        }
    } else {
        // ---- GEMM path ----
        __shared__ __align__(16) char smem[34816];
        __bf16 (*xs)[136] = (__bf16 (*)[136])smem;               // 17408 B
        __bf16 (*ot)[136] = (__bf16 (*)[136])(smem + 17408);     // 17408 B
        int gb = blockIdx.x - Ga;
        int tid = threadIdx.x;
        int rowbase = gb * 64;
        {   // cooperative stage: 2048 float4 over 512 threads, packed v4bf
            int i4 = tid;
#pragma unroll
            for (int rep = 0; rep < 4; ++rep, i4 += 512) {
                int r = i4 >> 5, c4 = i4 & 31;
                int gr = rowbase + r; if (gr > n - 1) gr = n - 1;
                float4 xv = *(const float4*)(x + (long)gr * 128 + c4 * 4);
                v4bf pk;
                pk[0] = (__bf16)xv.x; pk[1] = (__bf16)xv.y;
                pk[2] = (__bf16)xv.z; pk[3] = (__bf16)xv.w;
                *(v4bf*)(&xs[r][c4 * 4]) = pk;
            }
        }
        __syncthreads();
        int wv = tid >> 6;
        int lane = tid & 63;
        int m = lane & 15, quad = lane >> 4;
        int colbase = wv * 16;
        const __bf16* wcol = WT + (colbase + m) * 128;
        v8bf wf[4];
#pragma unroll
        for (int kk = 0; kk < 4; ++kk)
            wf[kk] = *(const v8bf*)(wcol + kk * 32 + quad * 8);
        v8bf wf2[4];
        if (wv < 4) {
            const __bf16* wcol2 = WT + (128 + m) * 128;   // a-strip cols 128..143
#pragma unroll
            for (int kk = 0; kk < 4; ++kk)
                wf2[kk] = *(const v8bf*)(wcol2 + kk * 32 + quad * 8);
        }
#pragma unroll
        for (int t = 0; t < 4; ++t) {
            int rb = t * 16;
            f32x4 acc = {0.f, 0.f, 0.f, 0.f};
#pragma unroll
            for (int kk = 0; kk < 4; ++kk) {
                v8bf a = *(const v8bf*)(&xs[rb + m][kk * 32 + quad * 8]);
                acc = __builtin_amdgcn_mfma_f32_16x16x32_bf16(a, wf[kk], acc, 0, 0, 0);
            }
#pragma unroll
            for (int r = 0; r < 4; ++r)
                ot[rb + quad * 4 + r][colbase + m] = (__bf16)acc[r];
        }
        if (wv < 4) {   // a-strip row-tile wv -> direct global (small)
            int rb = wv * 16;
            f32x4 acc = {0.f, 0.f, 0.f, 0.f};
#pragma unroll
            for (int kk = 0; kk < 4; ++kk) {
                v8bf a = *(const v8bf*)(&xs[rb + m][kk * 32 + quad * 8]);
                acc = __builtin_amdgcn_mfma_f32_16x16x32_bf16(a, wf2[kk], acc, 0, 0, 0);
            }
#pragma unroll
            for (int r = 0; r < 4; ++r) {
                int row = rowbase + rb + quad * 4 + r;
                if (row < n) {
                    if (m < 8) a_src[row * 8 + m] = acc[r];
                    else       a_dst[row * 8 + (m - 8)] = acc[r];
                }
            }
        }
        __syncthreads();
        // coalesced retiled store: 512 thr x 16 B x 2 passes = 64 rows x 256 B
        int r0 = tid >> 4, c8 = tid & 15;
#pragma unroll
        for (int pass = 0; pass < 2; ++pass) {
            int r = r0 + pass * 32;
            int gr = rowbase + r;
            if (gr < n) {
                v8bf vv = *(const v8bf*)(&ot[r][c8 * 8]);
                *(v8bf*)(xp16 + (long)gr * FEAT + c8 * 8) = vv;
            }
        }
    }
}

// 16 nodes per block: DIRECT coalesced load of the 16 nodes' slot lists
// (no slab scan, no filter atomics), then wave-per-node register
// aggregation + LayerNorm + store. Aggregation loop is the round-4/7
// champion, byte-identical.
__global__ __launch_bounds__(256) void k_ba(const int* __restrict__ nodelist,
                                            const int* __restrict__ nodecnt,
                                            const float* __restrict__ a_src,
                                            const float* __restrict__ a_dst,
                                            const __bf16* __restrict__ xp16,
                                            const float* __restrict__ bias,
                                            const float* __restrict__ gamma,
                                            const float* __restrict__ beta,
                                            const int* __restrict__ src,
                                            const int* __restrict__ dst,
                                            float* __restrict__ out, int n, int E) {
    __shared__ int slds[NPQ * CAP];       // 3 KB slot lists
    __shared__ int lc[NPQ];
    __shared__ float adst_s[NPQ * NHD];   // 512 B
    int tid = threadIdx.x;
    int node0 = (int)blockIdx.x * NPQ;
    if (tid < NPQ) {
        int nd = node0 + tid;
        lc[tid] = (nd < n) ? nodecnt[nd] : 0;
    }
    if (tid < NPQ * NHD) {
        int nd = node0 + (tid >> 3);
        adst_s[tid] = (nd < n) ? a_dst[nd * NHD + (tid & 7)] : 0.f;
    }
    // ---- build: direct coalesced copy of 16 node lists (768 ints) ----
    long gbase = (long)node0 * CAP;
    long glim = (long)n * CAP;
#pragma unroll
    for (int rep = 0; rep < 3; ++rep) {
        int i = tid + rep * 256;
        slds[i] = (gbase + i < glim) ? nodelist[gbase + i] : 0;
    }
    __syncthreads();
    // pad each list to a multiple of 8 with dummy id 0 (weight forced to 0)
    if (tid < NPQ) {
        int cc = lc[tid]; if (cc > CAP) cc = CAP;
        int pad = (cc + 7) & ~7; if (pad > CAP) pad = CAP;
        for (int p = cc; p < pad; ++p) slds[tid * CAP + p] = 0;
    }
    __syncthreads();

    int lane = tid & 63, wv = tid >> 6;
    int h = lane & 7, j8 = lane >> 3;
    float2 bs = *(const float2*)(bias + 2 * lane);
    float2 g  = *(const float2*)(gamma + 2 * lane);
    float2 bt = *(const float2*)(beta + 2 * lane);

    // ---- aggregate: wave wv handles nodes wv, wv+4, ... ----
    for (int i = wv; i < NPQ; i += 4) {
        int node = node0 + i;
        if (node >= n) break;
        int cnt = lc[i];
        float acc0 = 0.f, acc1 = 0.f, inv;

        if (cnt <= CAP) {
            const int* row = slds + i * CAP;
            float b_h = adst_s[i * NHD + h];
            float zacc = 0.f;
            for (int base = 0; base < cnt; base += 8) {
                int s_my = row[base + j8];          // padded: always valid
                float e = a_src[s_my * NHD + h] + b_h;
                e = e > 0.f ? e : NEG_SLOPE * e;
                float w_my = (base + j8 < cnt) ? __expf(e) : 0.f;
                zacc += w_my;
                int ss[8];
#pragma unroll
                for (int j = 0; j < 8; ++j) ss[j] = row[base + j];   // LDS broadcast
                float2 vals[8];
#pragma unroll
                for (int j = 0; j < 8; ++j) {
                    v2bf p = *(const v2bf*)(xp16 + (long)ss[j] * FEAT + 2 * lane);
                    vals[j] = make_float2((float)p[0], (float)p[1]);
                }
#pragma unroll
                for (int j = 0; j < 8; ++j) {
                    float w = __shfl(w_my, j * 8 + j8);
                    acc0 = fmaf(w, vals[j].x, acc0);
                    acc1 = fmaf(w, vals[j].y, acc1);
                }
            }
            zacc += __shfl_xor(zacc, 8);
            zacc += __shfl_xor(zacc, 16);
            zacc += __shfl_xor(zacc, 32);
            float z = __shfl(zacc, j8);
            inv = 1.f / z;
        } else {
            // ---- fallback (deg > CAP; never expected): rescan edge list ----
            float b_h = a_dst[node * NHD + j8];
            float z = 0.f;
            {   // self-loop
                float e = a_src[node * NHD + j8] + b_h;
                e = e > 0.f ? e : NEG_SLOPE * e;
                float w = __expf(e);
                z += w;
                v2bf p = *(const v2bf*)(xp16 + (long)node * FEAT + 2 * lane);
                acc0 = fmaf(w, (float)p[0], acc0);
                acc1 = fmaf(w, (float)p[1], acc1);
            }
            for (int base = 0; base < E; base += 64) {
                int e = base + lane;
                int sv = 0;
                bool mt = false;
                if (e < E) { mt = (dst[e] == node); if (mt) sv = src[e]; }
                unsigned long long mask = __ballot(mt);
                while (mask) {
                    int bl = __ffsll(mask) - 1;
                    mask &= mask - 1;
                    int s = __shfl(sv, bl);
                    float ee = a_src[s * NHD + j8] + b_h;
                    ee = ee > 0.f ? ee : NEG_SLOPE * ee;
                    float w = __expf(ee);
                    z += w;
                    v2bf p = *(const v2bf*)(xp16 + (long)s * FEAT + 2 * lane);
                    acc0 = fmaf(w, (float)p[0], acc0);
                    acc1 = fmaf(w, (float)p[1], acc1);
                }
            }
            inv = 1.f / z;
        }

        // ---- epilogue: normalize, bias, LayerNorm, store ----
        float v0 = acc0 * inv + bs.x;
        float v1 = acc1 * inv + bs.y;
        float ssum = v0 + v1;
        float ssq = v0 * v0 + v1 * v1;
#pragma unroll
        for (int o = 32; o > 0; o >>= 1) {
            ssum += __shfl_xor(ssum, o);
            ssq += __shfl_xor(ssq, o);
        }
        float mu = ssum * (1.0f / FEAT);
        float var = ssq * (1.0f / FEAT) - mu * mu;
        float rs = rsqrtf(var + LN_EPS);
        float2 o2;
        o2.x = (v0 - mu) * rs * g.x + bt.x;
        o2.y = (v1 - mu) * rs * g.y + bt.y;
        *(float2*)(out + (long)node * FEAT + 2 * lane) = o2;
    }
}

extern "C" void kernel_launch(void* const* d_in, const int* in_sizes, int n_in,
                              void* d_out, int out_size, void* d_ws, size_t ws_size,
                              hipStream_t stream) {
    const float* x = (const float*)d_in[0];
    const int* edge_index = (const int*)d_in[1];
    const float* W = (const float*)d_in[2];
    const float* att_src = (const float*)d_in[3];
    const float* att_dst = (const float*)d_in[4];
    const float* bias = (const float*)d_in[5];
    const float* gamma = (const float*)d_in[6];
    const float* beta = (const float*)d_in[7];
    float* out = (float*)d_out;

    int n = in_sizes[0] / F_IN;
    int E = in_sizes[1] / 2;
    const int* src = edge_index;
    const int* dst = edge_index + E;
    int Ga = (E + n + EPB - 1) / EPB;
    int Gg = (n + 63) / 64;
    int Gb = (n + NPQ - 1) / NPQ;
    int wtotal = WCOLS * 128; if (n > wtotal) wtotal = n;
    int Gw = (wtotal + 255) / 256;

    char* ws = (char*)d_ws;
    __bf16* WT   = (__bf16*)ws;                    ws += (size_t)WCOLS * 128 * 2;
    __bf16* xp16 = (__bf16*)ws;                    ws += (size_t)n * FEAT * 2;
    float* a_src = (float*)ws;                     ws += (size_t)n * NHD * 4;
    float* a_dst = (float*)ws;                     ws += (size_t)n * NHD * 4;
    int* nodelist = (int*)ws;                      ws += (size_t)n * CAP * 4;
    int* nodecnt = (int*)ws;                       ws += (size_t)n * 4;

    k_wt<<<Gw, 256, 0, stream>>>(W, att_src, att_dst, WT, nodecnt, n);
    k_fused<<<Ga + Gg, 512, 0, stream>>>(x, WT, xp16, a_src, a_dst,
                                         src, dst, nodelist, nodecnt, n, E, Ga);
    k_ba<<<Gb, 256, 0, stream>>>(nodelist, nodecnt, a_src, a_dst, xp16,
                                 bias, gamma, beta, src, dst, out, n, E);
}

// Round 12
// 146.675 us; speedup vs baseline: 1.2215x; 1.2215x over previous
//
#include <hip/hip_runtime.h>
#include <math.h>

#define F_IN 128
#define NHD 8
#define FEAT 128   // NHD*FO
#define NEG_SLOPE 0.2f
#define LN_EPS 1e-5f
#define BSH 7      // 128 nodes per bucket
#define BMSK 127
#define NPQ 16     // nodes per k_ba block (eighth of a bucket)
#define CAP 48     // per-node slot capacity in LDS; deg>CAP -> fallback
#define EPB 4096   // edges sorted per phase-A block (512 thr x 8)
#define NBMAX 512  // max buckets (n <= 65536)
#define BCAP 6144  // per-bucket slab capacity in reordered edge array
#define WCOLS 144  // 128 xp cols + 8 a_src cols + 8 a_dst cols

typedef __bf16 v8bf __attribute__((ext_vector_type(8)));
typedef __bf16 v4bf __attribute__((ext_vector_type(4)));
typedef __bf16 v2bf __attribute__((ext_vector_type(2)));
typedef float f32x4 __attribute__((ext_vector_type(4)));

// Build WT_ext[144][128]: cols 0..127 = W^T (bf16); cols 128..135 = W @ att_src
// folded per head; cols 136..143 = W @ att_dst. Also zeroes the global
// per-bucket cursors (stream-ordered before k_fused).
__global__ __launch_bounds__(256) void k_wt(const float* __restrict__ W,
                                            const float* __restrict__ att_src,
                                            const float* __restrict__ att_dst,
                                            __bf16* __restrict__ WT,
                                            int* __restrict__ gcnt, int NB) {
    int idx = blockIdx.x * 256 + threadIdx.x;   // 144*128 = 18432 total
    if (idx < NB) gcnt[idx] = 0;
    int c = idx >> 7, k = idx & 127;
    float v;
    if (c < 128) {
        v = W[k * 128 + c];
    } else if (c < 136) {
        int h = c - 128;
        float s = 0.f;
#pragma unroll
        for (int f = 0; f < 16; ++f) s += W[k * 128 + h * 16 + f] * att_src[h * 16 + f];
        v = s;
    } else {
        int h = c - 136;
        float s = 0.f;
#pragma unroll
        for (int f = 0; f < 16; ++f) s += W[k * 128 + h * 16 + f] * att_dst[h * 16 + f];
        v = s;
    }
    WT[c * 128 + k] = (__bf16)v;
}

// Fused: blocks [0,Ga) = block-local counting sort of 4096 edges by dst
// bucket, then direct scatter into the global bucket-contiguous slab.
// Blocks [Ga,..) = MFMA GEMM, 64 rows/block, 8 waves, LDS retile stores.
__global__ __launch_bounds__(512) void k_fused(const float* __restrict__ x,
                                               const __bf16* __restrict__ WT,
                                               __bf16* __restrict__ xp16,
                                               float* __restrict__ a_src,
                                               float* __restrict__ a_dst,
                                               const int* __restrict__ src,
                                               const int* __restrict__ dst,
                                               unsigned int* __restrict__ sorted2,
                                               int* __restrict__ gcnt,
                                               int n, int E, int Ga) {
    __shared__ __align__(16) char smem[34816];
    if ((int)blockIdx.x < Ga) {
        // ---- phase A: block-local counting sort + global scatter ----
        unsigned int* sorted_l = (unsigned int*)smem;            // 16384 B
        int* lcnt = (int*)(smem + 16384);                        // 2048 B
        int* loff = (int*)(smem + 16384 + 2048);                 // 2052 B
        int* wtot = (int*)(smem + 16384 + 2048 + 2052);          // 32 B
        int* wexcl = (int*)(smem + 16384 + 2048 + 2052 + 32);    // 32 B
        int* goff = (int*)(smem + 16384 + 2048 + 2052 + 64);     // 2048 B
        int NB = (n + BMSK) >> BSH;
        int tid = threadIdx.x, lane = tid & 63, wid = tid >> 6;
        long base0 = (long)blockIdx.x * EPB;
        long total = (long)E + n;
        if (tid < NB) lcnt[tid] = 0;
        __syncthreads();

        int s0[8], d0[8];
        bool val[8];
        long e0 = base0 + (long)tid * 8;
        if (e0 + 7 < E) {
            int4 sa = *(const int4*)(src + e0);
            int4 sb = *(const int4*)(src + e0 + 4);
            int4 da = *(const int4*)(dst + e0);
            int4 db = *(const int4*)(dst + e0 + 4);
            s0[0] = sa.x; s0[1] = sa.y; s0[2] = sa.z; s0[3] = sa.w;
            s0[4] = sb.x; s0[5] = sb.y; s0[6] = sb.z; s0[7] = sb.w;
            d0[0] = da.x; d0[1] = da.y; d0[2] = da.z; d0[3] = da.w;
            d0[4] = db.x; d0[5] = db.y; d0[6] = db.z; d0[7] = db.w;
#pragma unroll
            for (int j = 0; j < 8; ++j) val[j] = true;
        } else {
#pragma unroll
            for (int j = 0; j < 8; ++j) {
                long e = e0 + j;
                val[j] = (e < total);
                s0[j] = d0[j] = 0;
                if (val[j]) {
                    if (e < E) { s0[j] = src[e]; d0[j] = dst[e]; }
                    else { s0[j] = d0[j] = (int)(e - E); }
                }
            }
        }
#pragma unroll
        for (int j = 0; j < 8; ++j)
            if (val[j]) atomicAdd(&lcnt[d0[j] >> BSH], 1);
        __syncthreads();

        int v = (tid < NB) ? lcnt[tid] : 0;
        int xx = v;
#pragma unroll
        for (int o = 1; o < 64; o <<= 1) {
            int t2 = __shfl_up(xx, o);
            if (lane >= o) xx += t2;
        }
        if (lane == 63) wtot[wid] = xx;
        __syncthreads();
        if (wid == 0 && lane < 8) {
            int s = wtot[lane];
            int y = s;
#pragma unroll
            for (int o = 1; o < 8; o <<= 1) {
                int t2 = __shfl_up(y, o);
                if (lane >= o) y += t2;
            }
            wexcl[lane] = y - s;
        }
        __syncthreads();
        int excl = wexcl[wid] + xx - v;
        if (tid < NB) loff[tid] = excl;
        if (tid == NB - 1) loff[NB] = excl + v;
        __syncthreads();
        if (tid < NB) lcnt[tid] = loff[tid];   // cursor
        __syncthreads();
        // local scatter; pack bucket id into bits 23..31 (NB<=512, src<65536)
#pragma unroll
        for (int j = 0; j < 8; ++j) {
            if (val[j]) {
                int b = d0[j] >> BSH;
                int pos = atomicAdd(&lcnt[b], 1);
                sorted_l[pos] = ((unsigned)b << 23) | ((unsigned)s0[j] << 7) |
                                (unsigned)(d0[j] & BMSK);
            }
        }
        __syncthreads();
        // reserve global slab space per non-empty bucket
        if (tid < NB) {
            int len = loff[tid + 1] - loff[tid];
            goff[tid] = (len > 0) ? atomicAdd(&gcnt[tid], len) : 0;
        }
        __syncthreads();
        // copy runs to slab (consecutive i within a run -> coalesced stores)
        int tv = loff[NB];
        for (int i = tid; i < tv; i += 512) {
            unsigned int u = sorted_l[i];
            int b = (int)(u >> 23);
            int r = goff[b] + (i - loff[b]);
            if (r < BCAP)
                sorted2[(long)b * BCAP + r] = u & 0x7FFFFFu;
        }
    } else {
        // ---- GEMM path ----
        __bf16 (*xs)[136] = (__bf16 (*)[136])smem;               // 17408 B
        __bf16 (*ot)[136] = (__bf16 (*)[136])(smem + 17408);     // 17408 B
        int gb = blockIdx.x - Ga;
        int tid = threadIdx.x;
        int rowbase = gb * 64;
        {   // cooperative stage: 2048 float4 over 512 threads, packed v4bf
            int i4 = tid;
#pragma unroll
            for (int rep = 0; rep < 4; ++rep, i4 += 512) {
                int r = i4 >> 5, c4 = i4 & 31;
                int gr = rowbase + r; if (gr > n - 1) gr = n - 1;
                float4 xv = *(const float4*)(x + (long)gr * 128 + c4 * 4);
                v4bf pk;
                pk[0] = (__bf16)xv.x; pk[1] = (__bf16)xv.y;
                pk[2] = (__bf16)xv.z; pk[3] = (__bf16)xv.w;
                *(v4bf*)(&xs[r][c4 * 4]) = pk;
            }
        }
        __syncthreads();
        int wv = tid >> 6;
        int lane = tid & 63;
        int m = lane & 15, quad = lane >> 4;
        int colbase = wv * 16;
        const __bf16* wcol = WT + (colbase + m) * 128;
        v8bf wf[4];
#pragma unroll
        for (int kk = 0; kk < 4; ++kk)
            wf[kk] = *(const v8bf*)(wcol + kk * 32 + quad * 8);
        v8bf wf2[4];
        if (wv < 4) {
            const __bf16* wcol2 = WT + (128 + m) * 128;   // a-strip cols 128..143
#pragma unroll
            for (int kk = 0; kk < 4; ++kk)
                wf2[kk] = *(const v8bf*)(wcol2 + kk * 32 + quad * 8);
        }
#pragma unroll
        for (int t = 0; t < 4; ++t) {
            int rb = t * 16;
            f32x4 acc = {0.f, 0.f, 0.f, 0.f};
#pragma unroll
            for (int kk = 0; kk < 4; ++kk) {
                v8bf a = *(const v8bf*)(&xs[rb + m][kk * 32 + quad * 8]);
                acc = __builtin_amdgcn_mfma_f32_16x16x32_bf16(a, wf[kk], acc, 0, 0, 0);
            }
#pragma unroll
            for (int r = 0; r < 4; ++r)
                ot[rb + quad * 4 + r][colbase + m] = (__bf16)acc[r];
        }
        if (wv < 4) {   // a-strip row-tile wv -> direct global (small)
            int rb = wv * 16;
            f32x4 acc = {0.f, 0.f, 0.f, 0.f};
#pragma unroll
            for (int kk = 0; kk < 4; ++kk) {
                v8bf a = *(const v8bf*)(&xs[rb + m][kk * 32 + quad * 8]);
                acc = __builtin_amdgcn_mfma_f32_16x16x32_bf16(a, wf2[kk], acc, 0, 0, 0);
            }
#pragma unroll
            for (int r = 0; r < 4; ++r) {
                int row = rowbase + rb + quad * 4 + r;
                if (row < n) {
                    if (m < 8) a_src[row * 8 + m] = acc[r];
                    else       a_dst[row * 8 + (m - 8)] = acc[r];
                }
            }
        }
        __syncthreads();
        // coalesced retiled store: 512 thr x 16 B x 2 passes = 64 rows x 256 B
        int r0 = tid >> 4, c8 = tid & 15;
#pragma unroll
        for (int pass = 0; pass < 2; ++pass) {
            int r = r0 + pass * 32;
            int gr = rowbase + r;
            if (gr < n) {
                v8bf vv = *(const v8bf*)(&ot[r][c8 * 8]);
                *(v8bf*)(xp16 + (long)gr * FEAT + c8 * 8) = vv;
            }
        }
    }
}

// 8 blocks per 128-node bucket (16 nodes each): uint4-vectorized coalesced
// filter of the bucket slab into LDS slot lists (4 entries per load, 4x
// fewer scan iterations; atomics unchanged), then wave-per-node register
// aggregation + LayerNorm + store. Aggregation loop is the round-4/7
// champion, byte-identical — do not restructure.
__global__ __launch_bounds__(256) void k_ba(const unsigned int* __restrict__ sorted2,
                                            const int* __restrict__ bcnt,
                                            const float* __restrict__ a_src,
                                            const float* __restrict__ a_dst,
                                            const __bf16* __restrict__ xp16,
                                            const float* __restrict__ bias,
                                            const float* __restrict__ gamma,
                                            const float* __restrict__ beta,
                                            const int* __restrict__ src,
                                            const int* __restrict__ dst,
                                            float* __restrict__ out, int n, int E) {
    __shared__ int slds[NPQ * CAP];       // 3 KB slot lists
    __shared__ int lc[NPQ];
    __shared__ float adst_s[NPQ * NHD];   // 512 B
    int b = blockIdx.x >> 3;
    int q = blockIdx.x & 7;
    int tid = threadIdx.x;
    int node0 = (b << BSH) + q * NPQ;
    if (tid < NPQ) lc[tid] = 0;
    if (tid < NPQ * NHD) {
        int nd = node0 + (tid >> 3);
        adst_s[tid] = (nd < n) ? a_dst[nd * NHD + (tid & 7)] : 0.f;
    }
    __syncthreads();

    // ---- build: uint4 coalesced filter of the contiguous bucket slab ----
    int cnt_b = bcnt[b]; if (cnt_b > BCAP) cnt_b = BCAP;
    const unsigned int* sg = sorted2 + (long)b * BCAP;
    int qlo = q * NPQ;
    int cnt4 = cnt_b >> 2;
    for (int i4 = tid; i4 < cnt4; i4 += 256) {
        uint4 u4 = *(const uint4*)(sg + (i4 << 2));
        unsigned int uu[4] = {u4.x, u4.y, u4.z, u4.w};
#pragma unroll
        for (int k = 0; k < 4; ++k) {
            unsigned int u = uu[k];
            int dl = (int)(u & BMSK) - qlo;
            if ((unsigned)dl < (unsigned)NPQ) {
                int p = atomicAdd(&lc[dl], 1);
                if (p < CAP) slds[dl * CAP + p] = (int)(u >> BSH);
            }
        }
    }
    for (int i = (cnt4 << 2) + tid; i < cnt_b; i += 256) {   // tail
        unsigned int u = sg[i];
        int dl = (int)(u & BMSK) - qlo;
        if ((unsigned)dl < (unsigned)NPQ) {
            int p = atomicAdd(&lc[dl], 1);
            if (p < CAP) slds[dl * CAP + p] = (int)(u >> BSH);
        }
    }
    __syncthreads();
    // pad each list to a multiple of 8 with dummy id 0 (weight forced to 0)
    if (tid < NPQ) {
        int cc = lc[tid]; if (cc > CAP) cc = CAP;
        int pad = (cc + 7) & ~7; if (pad > CAP) pad = CAP;
        for (int p = cc; p < pad; ++p) slds[tid * CAP + p] = 0;
    }
    __syncthreads();

    int lane = tid & 63, wv = tid >> 6;
    int h = lane & 7, j8 = lane >> 3;
    float2 bs = *(const float2*)(bias + 2 * lane);
    float2 g  = *(const float2*)(gamma + 2 * lane);
    float2 bt = *(const float2*)(beta + 2 * lane);

    // ---- aggregate: wave wv handles nodes wv, wv+4, ... ----
    for (int i = wv; i < NPQ; i += 4) {
        int node = node0 + i;
        if (node >= n) break;
        int cnt = lc[i];
        float acc0 = 0.f, acc1 = 0.f, inv;

        if (cnt <= CAP) {
            const int* row = slds + i * CAP;
            float b_h = adst_s[i * NHD + h];
            float zacc = 0.f;
            for (int base = 0; base < cnt; base += 8) {
                int s_my = row[base + j8];          // padded: always valid
                float e = a_src[s_my * NHD + h] + b_h;
                e = e > 0.f ? e : NEG_SLOPE * e;
                float w_my = (base + j8 < cnt) ? __expf(e) : 0.f;
                zacc += w_my;
                int ss[8];
#pragma unroll
                for (int j = 0; j < 8; ++j) ss[j] = row[base + j];   // LDS broadcast
                float2 vals[8];
#pragma unroll
                for (int j = 0; j < 8; ++j) {
                    v2bf p = *(const v2bf*)(xp16 + (long)ss[j] * FEAT + 2 * lane);
                    vals[j] = make_float2((float)p[0], (float)p[1]);
                }
#pragma unroll
                for (int j = 0; j < 8; ++j) {
                    float w = __shfl(w_my, j * 8 + j8);
                    acc0 = fmaf(w, vals[j].x, acc0);
                    acc1 = fmaf(w, vals[j].y, acc1);
                }
            }
            zacc += __shfl_xor(zacc, 8);
            zacc += __shfl_xor(zacc, 16);
            zacc += __shfl_xor(zacc, 32);
            float z = __shfl(zacc, j8);
            inv = 1.f / z;
        } else {
            // ---- fallback (deg > CAP; never expected): rescan edge list ----
            float b_h = a_dst[node * NHD + j8];
            float z = 0.f;
            {   // self-loop
                float e = a_src[node * NHD + j8] + b_h;
                e = e > 0.f ? e : NEG_SLOPE * e;
                float w = __expf(e);
                z += w;
                v2bf p = *(const v2bf*)(xp16 + (long)node * FEAT + 2 * lane);
                acc0 = fmaf(w, (float)p[0], acc0);
                acc1 = fmaf(w, (float)p[1], acc1);
            }
            for (int base = 0; base < E; base += 64) {
                int e = base + lane;
                int sv = 0;
                bool mt = false;
                if (e < E) { mt = (dst[e] == node); if (mt) sv = src[e]; }
                unsigned long long mask = __ballot(mt);
                while (mask) {
                    int bl = __ffsll(mask) - 1;
                    mask &= mask - 1;
                    int s = __shfl(sv, bl);
                    float ee = a_src[s * NHD + j8] + b_h;
                    ee = ee > 0.f ? ee : NEG_SLOPE * ee;
                    float w = __expf(ee);
                    z += w;
                    v2bf p = *(const v2bf*)(xp16 + (long)s * FEAT + 2 * lane);
                    acc0 = fmaf(w, (float)p[0], acc0);
                    acc1 = fmaf(w, (float)p[1], acc1);
                }
            }
            inv = 1.f / z;
        }

        // ---- epilogue: normalize, bias, LayerNorm, store ----
        float v0 = acc0 * inv + bs.x;
        float v1 = acc1 * inv + bs.y;
        float ssum = v0 + v1;
        float ssq = v0 * v0 + v1 * v1;
#pragma unroll
        for (int o = 32; o > 0; o >>= 1) {
            ssum += __shfl_xor(ssum, o);
            ssq += __shfl_xor(ssq, o);
        }
        float mu = ssum * (1.0f / FEAT);
        float var = ssq * (1.0f / FEAT) - mu * mu;
        float rs = rsqrtf(var + LN_EPS);
        float2 o2;
        o2.x = (v0 - mu) * rs * g.x + bt.x;
        o2.y = (v1 - mu) * rs * g.y + bt.y;
        *(float2*)(out + (long)node * FEAT + 2 * lane) = o2;
    }
}

extern "C" void kernel_launch(void* const* d_in, const int* in_sizes, int n_in,
                              void* d_out, int out_size, void* d_ws, size_t ws_size,
                              hipStream_t stream) {
    const float* x = (const float*)d_in[0];
    const int* edge_index = (const int*)d_in[1];
    const float* W = (const float*)d_in[2];
    const float* att_src = (const float*)d_in[3];
    const float* att_dst = (const float*)d_in[4];
    const float* bias = (const float*)d_in[5];
    const float* gamma = (const float*)d_in[6];
    const float* beta = (const float*)d_in[7];
    float* out = (float*)d_out;

    int n = in_sizes[0] / F_IN;
    int E = in_sizes[1] / 2;
    const int* src = edge_index;
    const int* dst = edge_index + E;
    int NB = (n + BMSK) >> BSH;
    int Ga = (E + n + EPB - 1) / EPB;
    int Gg = (n + 63) / 64;

    char* ws = (char*)d_ws;
    __bf16* WT   = (__bf16*)ws;                    ws += (size_t)WCOLS * 128 * 2;
    __bf16* xp16 = (__bf16*)ws;                    ws += (size_t)n * FEAT * 2;
    float* a_src = (float*)ws;                     ws += (size_t)n * NHD * 4;
    float* a_dst = (float*)ws;                     ws += (size_t)n * NHD * 4;
    unsigned int* sorted2 = (unsigned int*)ws;     ws += (size_t)NB * BCAP * 4;
    int* gcnt = (int*)ws;                          ws += (size_t)NB * 4;

    k_wt<<<72, 256, 0, stream>>>(W, att_src, att_dst, WT, gcnt, NB);
    k_fused<<<Ga + Gg, 512, 0, stream>>>(x, WT, xp16, a_src, a_dst,
                                         src, dst, sorted2, gcnt, n, E, Ga);
    k_ba<<<NB * 8, 256, 0, stream>>>(sorted2, gcnt, a_src, a_dst, xp16,
                                     bias, gamma, beta, src, dst, out, n, E);
}